// Round 3
// baseline (104.778 us; speedup 1.0000x reference)
//
#include <hip/hip_runtime.h>

#define Ndim 128
#define Cdim 3
#define Hdim 256
#define Wdim 256
#define HW (Hdim * Wdim)
#define MAXNORM_F 5.371920351148152f

__device__ __forceinline__ void mm3f(const float a[3][3], const float b[3][3], float c[3][3]) {
    #pragma unroll
    for (int i = 0; i < 3; ++i)
        #pragma unroll
        for (int j = 0; j < 3; ++j) {
            float s = 0.0f;
            #pragma unroll
            for (int k = 0; k < 3; ++k) s = fmaf(a[i][k], b[k][j], s);
            c[i][j] = s;
        }
}

// One thread per batch element: expm of padded 3x3 affine matrix (fp32 Pade-13,
// matching the fp32 reference), write top 2 rows.
__global__ void expm_kernel(const float* __restrict__ theta, float* __restrict__ thOut) {
    int n = blockIdx.x * blockDim.x + threadIdx.x;
    if (n >= Ndim) return;

    const float b[14] = {6.476475253248e+16f, 3.238237626624e+16f, 7771770303897600.0f,
                         1187353796428800.0f, 129060195264000.0f, 10559470521600.0f,
                         670442572800.0f, 33522128640.0f, 1323241920.0f, 40840800.0f,
                         960960.0f, 16380.0f, 182.0f, 1.0f};

    float A[3][3];
    #pragma unroll
    for (int j = 0; j < 3; ++j) {
        A[0][j] = theta[n * 6 + j];
        A[1][j] = theta[n * 6 + 3 + j];
        A[2][j] = 0.0f;
    }

    float fro2 = 0.0f;
    #pragma unroll
    for (int i = 0; i < 3; ++i)
        #pragma unroll
        for (int j = 0; j < 3; ++j) fro2 = fmaf(A[i][j], A[i][j], fro2);
    float fro = sqrtf(fro2);

    float nsq = fmaxf(0.0f, ceilf(log2f(fro / MAXNORM_F)));
    int k = (int)nsq;
    float sc = exp2f(-nsq);
    #pragma unroll
    for (int i = 0; i < 3; ++i)
        #pragma unroll
        for (int j = 0; j < 3; ++j) A[i][j] *= sc;

    float A2[3][3], A4[3][3], A6[3][3], P[3][3], Wm[3][3], T[3][3], U[3][3], V[3][3];
    mm3f(A, A, A2);
    mm3f(A2, A2, A4);
    mm3f(A4, A2, A6);

    #pragma unroll
    for (int i = 0; i < 3; ++i)
        #pragma unroll
        for (int j = 0; j < 3; ++j)
            P[i][j] = b[13] * A6[i][j] + b[11] * A4[i][j] + b[9] * A2[i][j];
    mm3f(A6, P, T);
    #pragma unroll
    for (int i = 0; i < 3; ++i)
        #pragma unroll
        for (int j = 0; j < 3; ++j)
            Wm[i][j] = T[i][j] + b[7] * A6[i][j] + b[5] * A4[i][j] + b[3] * A2[i][j]
                       + (i == j ? b[1] : 0.0f);
    mm3f(A, Wm, U);

    #pragma unroll
    for (int i = 0; i < 3; ++i)
        #pragma unroll
        for (int j = 0; j < 3; ++j)
            P[i][j] = b[12] * A6[i][j] + b[10] * A4[i][j] + b[8] * A2[i][j];
    mm3f(A6, P, T);
    #pragma unroll
    for (int i = 0; i < 3; ++i)
        #pragma unroll
        for (int j = 0; j < 3; ++j)
            V[i][j] = T[i][j] + b[6] * A6[i][j] + b[4] * A4[i][j] + b[2] * A2[i][j]
                      + (i == j ? b[0] : 0.0f);

    // Solve (U+V) X = (V-U) : Gauss-Jordan with partial pivoting on [M | RHS]
    float M[3][6];
    #pragma unroll
    for (int i = 0; i < 3; ++i)
        #pragma unroll
        for (int j = 0; j < 3; ++j) {
            M[i][j]     = U[i][j] + V[i][j];
            M[i][j + 3] = V[i][j] - U[i][j];
        }
    #pragma unroll
    for (int col = 0; col < 3; ++col) {
        int piv = col;
        float best = fabsf(M[col][col]);
        for (int r = col + 1; r < 3; ++r) {
            float v = fabsf(M[r][col]);
            if (v > best) { best = v; piv = r; }
        }
        if (piv != col) {
            #pragma unroll
            for (int j = 0; j < 6; ++j) {
                float t = M[col][j]; M[col][j] = M[piv][j]; M[piv][j] = t;
            }
        }
        float inv = 1.0f / M[col][col];
        #pragma unroll
        for (int j = 0; j < 6; ++j) M[col][j] *= inv;
        #pragma unroll
        for (int r = 0; r < 3; ++r) {
            if (r == col) continue;
            float f = M[r][col];
            #pragma unroll
            for (int j = 0; j < 6; ++j) M[r][j] -= f * M[col][j];
        }
    }
    float R[3][3];
    #pragma unroll
    for (int i = 0; i < 3; ++i)
        #pragma unroll
        for (int j = 0; j < 3; ++j) R[i][j] = M[i][j + 3];

    for (int i = 0; i < 16; ++i) {
        if (i < k) {
            float Rn[3][3];
            mm3f(R, R, Rn);
            #pragma unroll
            for (int a = 0; a < 3; ++a)
                #pragma unroll
                for (int c = 0; c < 3; ++c) R[a][c] = Rn[a][c];
        }
    }

    #pragma unroll
    for (int j = 0; j < 3; ++j) {
        thOut[n * 6 + j]     = (float)R[0][j];
        thOut[n * 6 + 3 + j] = (float)R[1][j];
    }
}

// Fused affine_grid + bilinear grid_sample (zeros padding, align_corners=True).
// 4 consecutive output pixels per thread: block = 256(w) x 4(h) tile; all 16
// corner offsets/weights computed first, 16 independent loads per channel in
// flight (MLP to hide L2 latency), float4 stores. XCD-chunked swizzle keeps
// each XCD on 16 whole images (bilinear row overlap hits XCD-local L2).
__global__ __launch_bounds__(256) void sample_kernel(const float* __restrict__ x,
                                                     const float* __restrict__ th,
                                                     float* __restrict__ out) {
    // nwg = 128 images * 64 row-tiles = 8192, divisible by 8 -> bijective swizzle
    const int nwg_per_xcd = (Ndim * (Hdim / 4)) / 8;  // 1024
    int bid = blockIdx.x;
    int wgid = (bid & 7) * nwg_per_xcd + (bid >> 3);

    int thr = wgid & 63;   // row-tile within image (H/4 = 64)
    int n   = wgid >> 6;   // image

    int tid  = threadIdx.x;
    int lane = tid & 63;
    int h  = (thr << 2) + (tid >> 6);
    int w0 = lane << 2;    // 4 consecutive pixels per thread

    const float* t = th + n * 6;
    float t0 = t[0], t1 = t[1], t2 = t[2], t3 = t[3], t4 = t[4], t5 = t[5];

    float gy = fmaf((float)h, 2.0f / (float)(Hdim - 1), -1.0f);
    // ix(w) = ((t0*gx + t1*gy + t2) + 1) * 0.5*(W-1), gx = w*2/(W-1) - 1
    //       = ixb + w * t0   (since (2/(W-1)) * 0.5*(W-1) == 1)
    float ixb = (fmaf(t1, gy, t2) - t0 + 1.0f) * (0.5f * (float)(Wdim - 1));
    float iyb = (fmaf(t4, gy, t5) - t3 + 1.0f) * (0.5f * (float)(Hdim - 1));

    int   off[4][4];
    float wt[4][4];
    #pragma unroll
    for (int p = 0; p < 4; ++p) {
        float fw = (float)(w0 + p);
        float ix = fmaf(fw, t0, ixb);
        float iy = fmaf(fw, t3, iyb);

        float ix0f = floorf(ix), iy0f = floorf(iy);
        int ix0 = (int)ix0f, iy0 = (int)iy0f;
        int ix1 = ix0 + 1, iy1 = iy0 + 1;

        float wx1 = ix - ix0f, wx0 = 1.0f - wx1;
        float wy1 = iy - iy0f, wy0 = 1.0f - wy1;

        float mx0 = (ix0 >= 0 && ix0 < Wdim) ? 1.0f : 0.0f;
        float mx1 = (ix1 >= 0 && ix1 < Wdim) ? 1.0f : 0.0f;
        float my0 = (iy0 >= 0 && iy0 < Hdim) ? 1.0f : 0.0f;
        float my1 = (iy1 >= 0 && iy1 < Hdim) ? 1.0f : 0.0f;

        int xc0 = min(max(ix0, 0), Wdim - 1);
        int xc1 = min(max(ix1, 0), Wdim - 1);
        int yc0 = min(max(iy0, 0), Hdim - 1);
        int yc1 = min(max(iy1, 0), Hdim - 1);

        off[p][0] = yc0 * Wdim + xc0;
        off[p][1] = yc0 * Wdim + xc1;
        off[p][2] = yc1 * Wdim + xc0;
        off[p][3] = yc1 * Wdim + xc1;
        wt[p][0] = wy0 * wx0 * my0 * mx0;
        wt[p][1] = wy0 * wx1 * my0 * mx1;
        wt[p][2] = wy1 * wx0 * my1 * mx0;
        wt[p][3] = wy1 * wx1 * my1 * mx1;
    }

    size_t nbase = (size_t)n * Cdim * HW;
    size_t opix  = (size_t)h * Wdim + w0;

    #pragma unroll
    for (int c = 0; c < Cdim; ++c) {
        const float* img = x + nbase + (size_t)c * HW;
        float v[4][4];
        #pragma unroll
        for (int p = 0; p < 4; ++p)
            #pragma unroll
            for (int q = 0; q < 4; ++q)
                v[p][q] = img[off[p][q]];

        float4 r;
        r.x = fmaf(v[0][0], wt[0][0], fmaf(v[0][1], wt[0][1], fmaf(v[0][2], wt[0][2], v[0][3] * wt[0][3])));
        r.y = fmaf(v[1][0], wt[1][0], fmaf(v[1][1], wt[1][1], fmaf(v[1][2], wt[1][2], v[1][3] * wt[1][3])));
        r.z = fmaf(v[2][0], wt[2][0], fmaf(v[2][1], wt[2][1], fmaf(v[2][2], wt[2][2], v[2][3] * wt[2][3])));
        r.w = fmaf(v[3][0], wt[3][0], fmaf(v[3][1], wt[3][1], fmaf(v[3][2], wt[3][2], v[3][3] * wt[3][3])));

        *reinterpret_cast<float4*>(out + nbase + (size_t)c * HW + opix) = r;
    }
}

extern "C" void kernel_launch(void* const* d_in, const int* in_sizes, int n_in,
                              void* d_out, int out_size, void* d_ws, size_t ws_size,
                              hipStream_t stream) {
    const float* x     = (const float*)d_in[0];
    const float* theta = (const float*)d_in[1];
    float* out = (float*)d_out;
    float* th  = (float*)d_ws;  // 128*6 floats of scratch

    expm_kernel<<<1, 128, 0, stream>>>(theta, th);

    int nblocks = Ndim * (Hdim / 4);  // 8192
    sample_kernel<<<nblocks, 256, 0, stream>>>(x, th, out);
}

// Round 4
// 67.839 us; speedup vs baseline: 1.5445x; 1.5445x over previous
//
#include <hip/hip_runtime.h>

#define Ndim 128
#define Cdim 3
#define Hdim 256
#define Wdim 256
#define HW (Hdim * Wdim)
#define MAXNORM_F 5.371920351148152f

__device__ __forceinline__ void mm3f(const float a[3][3], const float b[3][3], float c[3][3]) {
    #pragma unroll
    for (int i = 0; i < 3; ++i)
        #pragma unroll
        for (int j = 0; j < 3; ++j) {
            float s = 0.0f;
            #pragma unroll
            for (int k = 0; k < 3; ++k) s = fmaf(a[i][k], b[k][j], s);
            c[i][j] = s;
        }
}

// One thread per batch element: expm of padded 3x3 affine matrix (fp32 Pade-13,
// matching the fp32 reference), write top 2 rows.
__global__ void expm_kernel(const float* __restrict__ theta, float* __restrict__ thOut) {
    int n = blockIdx.x * blockDim.x + threadIdx.x;
    if (n >= Ndim) return;

    const float b[14] = {6.476475253248e+16f, 3.238237626624e+16f, 7771770303897600.0f,
                         1187353796428800.0f, 129060195264000.0f, 10559470521600.0f,
                         670442572800.0f, 33522128640.0f, 1323241920.0f, 40840800.0f,
                         960960.0f, 16380.0f, 182.0f, 1.0f};

    float A[3][3];
    #pragma unroll
    for (int j = 0; j < 3; ++j) {
        A[0][j] = theta[n * 6 + j];
        A[1][j] = theta[n * 6 + 3 + j];
        A[2][j] = 0.0f;
    }

    float fro2 = 0.0f;
    #pragma unroll
    for (int i = 0; i < 3; ++i)
        #pragma unroll
        for (int j = 0; j < 3; ++j) fro2 = fmaf(A[i][j], A[i][j], fro2);
    float fro = sqrtf(fro2);

    float nsq = fmaxf(0.0f, ceilf(log2f(fro / MAXNORM_F)));
    int k = (int)nsq;
    float sc = exp2f(-nsq);
    #pragma unroll
    for (int i = 0; i < 3; ++i)
        #pragma unroll
        for (int j = 0; j < 3; ++j) A[i][j] *= sc;

    float A2[3][3], A4[3][3], A6[3][3], P[3][3], Wm[3][3], T[3][3], U[3][3], V[3][3];
    mm3f(A, A, A2);
    mm3f(A2, A2, A4);
    mm3f(A4, A2, A6);

    #pragma unroll
    for (int i = 0; i < 3; ++i)
        #pragma unroll
        for (int j = 0; j < 3; ++j)
            P[i][j] = b[13] * A6[i][j] + b[11] * A4[i][j] + b[9] * A2[i][j];
    mm3f(A6, P, T);
    #pragma unroll
    for (int i = 0; i < 3; ++i)
        #pragma unroll
        for (int j = 0; j < 3; ++j)
            Wm[i][j] = T[i][j] + b[7] * A6[i][j] + b[5] * A4[i][j] + b[3] * A2[i][j]
                       + (i == j ? b[1] : 0.0f);
    mm3f(A, Wm, U);

    #pragma unroll
    for (int i = 0; i < 3; ++i)
        #pragma unroll
        for (int j = 0; j < 3; ++j)
            P[i][j] = b[12] * A6[i][j] + b[10] * A4[i][j] + b[8] * A2[i][j];
    mm3f(A6, P, T);
    #pragma unroll
    for (int i = 0; i < 3; ++i)
        #pragma unroll
        for (int j = 0; j < 3; ++j)
            V[i][j] = T[i][j] + b[6] * A6[i][j] + b[4] * A4[i][j] + b[2] * A2[i][j]
                      + (i == j ? b[0] : 0.0f);

    // Solve (U+V) X = (V-U) : Gauss-Jordan with partial pivoting on [M | RHS]
    float M[3][6];
    #pragma unroll
    for (int i = 0; i < 3; ++i)
        #pragma unroll
        for (int j = 0; j < 3; ++j) {
            M[i][j]     = U[i][j] + V[i][j];
            M[i][j + 3] = V[i][j] - U[i][j];
        }
    #pragma unroll
    for (int col = 0; col < 3; ++col) {
        int piv = col;
        float best = fabsf(M[col][col]);
        for (int r = col + 1; r < 3; ++r) {
            float v = fabsf(M[r][col]);
            if (v > best) { best = v; piv = r; }
        }
        if (piv != col) {
            #pragma unroll
            for (int j = 0; j < 6; ++j) {
                float t = M[col][j]; M[col][j] = M[piv][j]; M[piv][j] = t;
            }
        }
        float inv = 1.0f / M[col][col];
        #pragma unroll
        for (int j = 0; j < 6; ++j) M[col][j] *= inv;
        #pragma unroll
        for (int r = 0; r < 3; ++r) {
            if (r == col) continue;
            float f = M[r][col];
            #pragma unroll
            for (int j = 0; j < 6; ++j) M[r][j] -= f * M[col][j];
        }
    }
    float R[3][3];
    #pragma unroll
    for (int i = 0; i < 3; ++i)
        #pragma unroll
        for (int j = 0; j < 3; ++j) R[i][j] = M[i][j + 3];

    for (int i = 0; i < 16; ++i) {
        if (i < k) {
            float Rn[3][3];
            mm3f(R, R, Rn);
            #pragma unroll
            for (int a = 0; a < 3; ++a)
                #pragma unroll
                for (int c = 0; c < 3; ++c) R[a][c] = Rn[a][c];
        }
    }

    #pragma unroll
    for (int j = 0; j < 3; ++j) {
        thOut[n * 6 + j]     = (float)R[0][j];
        thOut[n * 6 + 3 + j] = (float)R[1][j];
    }
}

// Fused affine_grid + bilinear grid_sample (zeros padding, align_corners=True).
// Tile = 64(w) x 8(h) per 256-thread block; each thread handles 2 vertically
// adjacent pixels (same w, rows h and h+1). Lane-to-lane stride stays 4B
// (fully coalesced gathers). All 24 gathers (2 px x 4 corners x 3 ch) are
// issued into named registers BEFORE any FMA consumes -> single latency
// exposure per wave instead of 3 dependent batches. Non-temporal stores keep
// x resident in L2/L3. XCD-chunked bijective swizzle: each XCD owns 16 whole
// images (bilinear row overlap stays in XCD-local L2).
__global__ __launch_bounds__(256) void sample_kernel(const float* __restrict__ x,
                                                     const float* __restrict__ th,
                                                     float* __restrict__ out) {
    // nwg = 4 (w-tiles) * 32 (h-tiles) * 128 (images) = 16384, divisible by 8
    const int nwg_per_xcd = (Ndim * (Hdim / 8) * (Wdim / 64)) / 8;  // 2048
    int bid = blockIdx.x;
    int wgid = (bid & 7) * nwg_per_xcd + (bid >> 3);

    int tw  = wgid & 3;          // w-tile   (W/64 = 4)
    int thr = (wgid >> 2) & 31;  // h-tile   (H/8  = 32)
    int n   = wgid >> 7;         // image

    int tid  = threadIdx.x;
    int lane = tid & 63;
    int w  = (tw << 6) + lane;
    int h0 = (thr << 3) + ((tid >> 6) << 1);  // rows h0, h0+1

    const float* t = th + n * 6;
    float t0 = t[0], t1 = t[1], t2 = t[2], t3 = t[3], t4 = t[4], t5 = t[5];

    float fw = (float)w;
    // ix(h,w) = ixb + w*t0 + gy*(t1*0.5*(W-1));  gx = w*2/(W-1)-1 folds to w*t0
    float ixc = (t2 - t0 + 1.0f) * (0.5f * (float)(Wdim - 1));
    float iyc = (t5 - t3 + 1.0f) * (0.5f * (float)(Hdim - 1));

    int   off[2][4];
    float wt[2][4];
    #pragma unroll
    for (int p = 0; p < 2; ++p) {
        float gy = fmaf((float)(h0 + p), 2.0f / (float)(Hdim - 1), -1.0f);
        float ix = fmaf(fw, t0, fmaf(t1 * (0.5f * (float)(Wdim - 1)), gy, ixc));
        float iy = fmaf(fw, t3, fmaf(t4 * (0.5f * (float)(Hdim - 1)), gy, iyc));

        float ix0f = floorf(ix), iy0f = floorf(iy);
        int ix0 = (int)ix0f, iy0 = (int)iy0f;
        int ix1 = ix0 + 1, iy1 = iy0 + 1;

        float wx1 = ix - ix0f, wx0 = 1.0f - wx1;
        float wy1 = iy - iy0f, wy0 = 1.0f - wy1;

        float mx0 = (ix0 >= 0 && ix0 < Wdim) ? 1.0f : 0.0f;
        float mx1 = (ix1 >= 0 && ix1 < Wdim) ? 1.0f : 0.0f;
        float my0 = (iy0 >= 0 && iy0 < Hdim) ? 1.0f : 0.0f;
        float my1 = (iy1 >= 0 && iy1 < Hdim) ? 1.0f : 0.0f;

        int xc0 = min(max(ix0, 0), Wdim - 1);
        int xc1 = min(max(ix1, 0), Wdim - 1);
        int yc0 = min(max(iy0, 0), Hdim - 1);
        int yc1 = min(max(iy1, 0), Hdim - 1);

        off[p][0] = yc0 * Wdim + xc0;
        off[p][1] = yc0 * Wdim + xc1;
        off[p][2] = yc1 * Wdim + xc0;
        off[p][3] = yc1 * Wdim + xc1;
        wt[p][0] = wy0 * wx0 * my0 * mx0;
        wt[p][1] = wy0 * wx1 * my0 * mx1;
        wt[p][2] = wy1 * wx0 * my1 * mx0;
        wt[p][3] = wy1 * wx1 * my1 * mx1;
    }

    size_t nbase = (size_t)n * Cdim * HW;
    const float* img0 = x + nbase;
    const float* img1 = img0 + HW;
    const float* img2 = img1 + HW;

    // Issue all 24 independent gathers before any consumption.
    float a00 = img0[off[0][0]], a01 = img0[off[0][1]], a02 = img0[off[0][2]], a03 = img0[off[0][3]];
    float a10 = img0[off[1][0]], a11 = img0[off[1][1]], a12 = img0[off[1][2]], a13 = img0[off[1][3]];
    float b00 = img1[off[0][0]], b01 = img1[off[0][1]], b02 = img1[off[0][2]], b03 = img1[off[0][3]];
    float b10 = img1[off[1][0]], b11 = img1[off[1][1]], b12 = img1[off[1][2]], b13 = img1[off[1][3]];
    float c00 = img2[off[0][0]], c01 = img2[off[0][1]], c02 = img2[off[0][2]], c03 = img2[off[0][3]];
    float c10 = img2[off[1][0]], c11 = img2[off[1][1]], c12 = img2[off[1][2]], c13 = img2[off[1][3]];

    float r0a = fmaf(a00, wt[0][0], fmaf(a01, wt[0][1], fmaf(a02, wt[0][2], a03 * wt[0][3])));
    float r1a = fmaf(a10, wt[1][0], fmaf(a11, wt[1][1], fmaf(a12, wt[1][2], a13 * wt[1][3])));
    float r0b = fmaf(b00, wt[0][0], fmaf(b01, wt[0][1], fmaf(b02, wt[0][2], b03 * wt[0][3])));
    float r1b = fmaf(b10, wt[1][0], fmaf(b11, wt[1][1], fmaf(b12, wt[1][2], b13 * wt[1][3])));
    float r0c = fmaf(c00, wt[0][0], fmaf(c01, wt[0][1], fmaf(c02, wt[0][2], c03 * wt[0][3])));
    float r1c = fmaf(c10, wt[1][0], fmaf(c11, wt[1][1], fmaf(c12, wt[1][2], c13 * wt[1][3])));

    size_t p0 = (size_t)h0 * Wdim + w;
    size_t p1 = p0 + Wdim;
    __builtin_nontemporal_store(r0a, out + nbase + p0);
    __builtin_nontemporal_store(r1a, out + nbase + p1);
    __builtin_nontemporal_store(r0b, out + nbase + HW + p0);
    __builtin_nontemporal_store(r1b, out + nbase + HW + p1);
    __builtin_nontemporal_store(r0c, out + nbase + 2 * HW + p0);
    __builtin_nontemporal_store(r1c, out + nbase + 2 * HW + p1);
}

extern "C" void kernel_launch(void* const* d_in, const int* in_sizes, int n_in,
                              void* d_out, int out_size, void* d_ws, size_t ws_size,
                              hipStream_t stream) {
    const float* x     = (const float*)d_in[0];
    const float* theta = (const float*)d_in[1];
    float* out = (float*)d_out;
    float* th  = (float*)d_ws;  // 128*6 floats of scratch

    expm_kernel<<<1, 128, 0, stream>>>(theta, th);

    int nblocks = Ndim * (Hdim / 8) * (Wdim / 64);  // 16384
    sample_kernel<<<nblocks, 256, 0, stream>>>(x, th, out);
}

// Round 5
// 44.814 us; speedup vs baseline: 2.3380x; 1.5138x over previous
//
#include <hip/hip_runtime.h>

#define Ndim 128
#define Cdim 3
#define Hdim 256
#define Wdim 256
#define HW (Hdim * Wdim)
#define MAXNORM_F 5.371920351148152f

typedef float vf2 __attribute__((ext_vector_type(2)));

__device__ __forceinline__ void mm3f(const float a[3][3], const float b[3][3], float c[3][3]) {
    #pragma unroll
    for (int i = 0; i < 3; ++i)
        #pragma unroll
        for (int j = 0; j < 3; ++j) {
            float s = 0.0f;
            #pragma unroll
            for (int k = 0; k < 3; ++k) s = fmaf(a[i][k], b[k][j], s);
            c[i][j] = s;
        }
}

// One thread per batch element: expm of padded 3x3 affine matrix (fp32 Pade-13,
// matching the fp32 reference), write top 2 rows.
__global__ void expm_kernel(const float* __restrict__ theta, float* __restrict__ thOut) {
    int n = blockIdx.x * blockDim.x + threadIdx.x;
    if (n >= Ndim) return;

    const float b[14] = {6.476475253248e+16f, 3.238237626624e+16f, 7771770303897600.0f,
                         1187353796428800.0f, 129060195264000.0f, 10559470521600.0f,
                         670442572800.0f, 33522128640.0f, 1323241920.0f, 40840800.0f,
                         960960.0f, 16380.0f, 182.0f, 1.0f};

    float A[3][3];
    #pragma unroll
    for (int j = 0; j < 3; ++j) {
        A[0][j] = theta[n * 6 + j];
        A[1][j] = theta[n * 6 + 3 + j];
        A[2][j] = 0.0f;
    }

    float fro2 = 0.0f;
    #pragma unroll
    for (int i = 0; i < 3; ++i)
        #pragma unroll
        for (int j = 0; j < 3; ++j) fro2 = fmaf(A[i][j], A[i][j], fro2);
    float fro = sqrtf(fro2);

    float nsq = fmaxf(0.0f, ceilf(log2f(fro / MAXNORM_F)));
    int k = (int)nsq;
    float sc = exp2f(-nsq);
    #pragma unroll
    for (int i = 0; i < 3; ++i)
        #pragma unroll
        for (int j = 0; j < 3; ++j) A[i][j] *= sc;

    float A2[3][3], A4[3][3], A6[3][3], P[3][3], Wm[3][3], T[3][3], U[3][3], V[3][3];
    mm3f(A, A, A2);
    mm3f(A2, A2, A4);
    mm3f(A4, A2, A6);

    #pragma unroll
    for (int i = 0; i < 3; ++i)
        #pragma unroll
        for (int j = 0; j < 3; ++j)
            P[i][j] = b[13] * A6[i][j] + b[11] * A4[i][j] + b[9] * A2[i][j];
    mm3f(A6, P, T);
    #pragma unroll
    for (int i = 0; i < 3; ++i)
        #pragma unroll
        for (int j = 0; j < 3; ++j)
            Wm[i][j] = T[i][j] + b[7] * A6[i][j] + b[5] * A4[i][j] + b[3] * A2[i][j]
                       + (i == j ? b[1] : 0.0f);
    mm3f(A, Wm, U);

    #pragma unroll
    for (int i = 0; i < 3; ++i)
        #pragma unroll
        for (int j = 0; j < 3; ++j)
            P[i][j] = b[12] * A6[i][j] + b[10] * A4[i][j] + b[8] * A2[i][j];
    mm3f(A6, P, T);
    #pragma unroll
    for (int i = 0; i < 3; ++i)
        #pragma unroll
        for (int j = 0; j < 3; ++j)
            V[i][j] = T[i][j] + b[6] * A6[i][j] + b[4] * A4[i][j] + b[2] * A2[i][j]
                      + (i == j ? b[0] : 0.0f);

    // Solve (U+V) X = (V-U) : Gauss-Jordan with partial pivoting on [M | RHS]
    float M[3][6];
    #pragma unroll
    for (int i = 0; i < 3; ++i)
        #pragma unroll
        for (int j = 0; j < 3; ++j) {
            M[i][j]     = U[i][j] + V[i][j];
            M[i][j + 3] = V[i][j] - U[i][j];
        }
    #pragma unroll
    for (int col = 0; col < 3; ++col) {
        int piv = col;
        float best = fabsf(M[col][col]);
        for (int r = col + 1; r < 3; ++r) {
            float v = fabsf(M[r][col]);
            if (v > best) { best = v; piv = r; }
        }
        if (piv != col) {
            #pragma unroll
            for (int j = 0; j < 6; ++j) {
                float t = M[col][j]; M[col][j] = M[piv][j]; M[piv][j] = t;
            }
        }
        float inv = 1.0f / M[col][col];
        #pragma unroll
        for (int j = 0; j < 6; ++j) M[col][j] *= inv;
        #pragma unroll
        for (int r = 0; r < 3; ++r) {
            if (r == col) continue;
            float f = M[r][col];
            #pragma unroll
            for (int j = 0; j < 6; ++j) M[r][j] -= f * M[col][j];
        }
    }
    float R[3][3];
    #pragma unroll
    for (int i = 0; i < 3; ++i)
        #pragma unroll
        for (int j = 0; j < 3; ++j) R[i][j] = M[i][j + 3];

    for (int i = 0; i < 16; ++i) {
        if (i < k) {
            float Rn[3][3];
            mm3f(R, R, Rn);
            #pragma unroll
            for (int a = 0; a < 3; ++a)
                #pragma unroll
                for (int c = 0; c < 3; ++c) R[a][c] = Rn[a][c];
        }
    }

    #pragma unroll
    for (int j = 0; j < 3; ++j) {
        thOut[n * 6 + j]     = (float)R[0][j];
        thOut[n * 6 + 3 + j] = (float)R[1][j];
    }
}

// Fused affine_grid + bilinear grid_sample (zeros padding, align_corners=True).
// Tile = 64(w) x 8(h); each thread does 2 vertically adjacent pixels.
// KEY CHANGE vs R4: the two x-corners (ix0, ix0+1) are loaded as ONE 8-byte
// pair (global_load_dwordx2) at base bx = clamp(ix0, 0, W-2). When ix0 != bx
// (edge/OOB), the pair is consumed with SWAPPED weights; the invalid corner's
// weight is already 0 from the mask. 24 dword gathers -> 12 dwordx2 gathers:
// halves VMEM instruction issue (the measured bottleneck), same bytes/lines.
__global__ __launch_bounds__(256) void sample_kernel(const float* __restrict__ x,
                                                     const float* __restrict__ th,
                                                     float* __restrict__ out) {
    // nwg = 4 (w-tiles) * 32 (h-tiles) * 128 (images) = 16384, divisible by 8
    const int nwg_per_xcd = (Ndim * (Hdim / 8) * (Wdim / 64)) / 8;  // 2048
    int bid = blockIdx.x;
    int wgid = (bid & 7) * nwg_per_xcd + (bid >> 3);

    int tw  = wgid & 3;          // w-tile   (W/64 = 4)
    int thr = (wgid >> 2) & 31;  // h-tile   (H/8  = 32)
    int n   = wgid >> 7;         // image

    int tid  = threadIdx.x;
    int lane = tid & 63;
    int w  = (tw << 6) + lane;
    int h0 = (thr << 3) + ((tid >> 6) << 1);  // rows h0, h0+1

    const float* t = th + n * 6;
    float t0 = t[0], t1 = t[1], t2 = t[2], t3 = t[3], t4 = t[4], t5 = t[5];

    float fw = (float)w;
    float ixc = (t2 - t0 + 1.0f) * (0.5f * (float)(Wdim - 1));
    float iyc = (t5 - t3 + 1.0f) * (0.5f * (float)(Hdim - 1));

    int   eoff[2][2];   // [pixel][row] element offset of the x-pair base
    float sw[2][4];     // swapped-as-needed weights: {r0x0, r0x1, r1x0, r1x1}
    #pragma unroll
    for (int p = 0; p < 2; ++p) {
        float gy = fmaf((float)(h0 + p), 2.0f / (float)(Hdim - 1), -1.0f);
        float ix = fmaf(fw, t0, fmaf(t1 * (0.5f * (float)(Wdim - 1)), gy, ixc));
        float iy = fmaf(fw, t3, fmaf(t4 * (0.5f * (float)(Hdim - 1)), gy, iyc));

        float ix0f = floorf(ix), iy0f = floorf(iy);
        int ix0 = (int)ix0f, iy0 = (int)iy0f;
        int ix1 = ix0 + 1, iy1 = iy0 + 1;

        float wx1 = ix - ix0f, wx0 = 1.0f - wx1;
        float wy1 = iy - iy0f, wy0 = 1.0f - wy1;

        float mx0 = (ix0 >= 0 && ix0 < Wdim) ? 1.0f : 0.0f;
        float mx1 = (ix1 >= 0 && ix1 < Wdim) ? 1.0f : 0.0f;
        float my0 = (iy0 >= 0 && iy0 < Hdim) ? 1.0f : 0.0f;
        float my1 = (iy1 >= 0 && iy1 < Hdim) ? 1.0f : 0.0f;

        int bx  = min(max(ix0, 0), Wdim - 2);   // pair base, [0, W-2]
        int yc0 = min(max(iy0, 0), Hdim - 1);
        int yc1 = min(max(iy1, 0), Hdim - 1);
        bool swap = (ix0 != bx);                // clamped -> consume swapped

        float a0 = wy0 * wx0 * my0 * mx0;  // weight for corner x0, row y0
        float a1 = wy0 * wx1 * my0 * mx1;  // x1, y0
        float a2 = wy1 * wx0 * my1 * mx0;  // x0, y1
        float a3 = wy1 * wx1 * my1 * mx1;  // x1, y1

        sw[p][0] = swap ? a1 : a0;   // weight applied to pair lane .x, row y0
        sw[p][1] = swap ? a0 : a1;   // .y, row y0
        sw[p][2] = swap ? a3 : a2;   // .x, row y1
        sw[p][3] = swap ? a2 : a3;   // .y, row y1

        eoff[p][0] = yc0 * Wdim + bx;
        eoff[p][1] = yc1 * Wdim + bx;
    }

    size_t nbase = (size_t)n * Cdim * HW;
    const float* img0 = x + nbase;
    const float* img1 = img0 + HW;
    const float* img2 = img1 + HW;

    // 12 independent 8-byte gathers (2 px * 2 rows * 3 ch), issued together.
    vf2 A0, A1, A2v, A3, B0, B1, B2, B3, C0, C1, C2, C3;
    __builtin_memcpy(&A0,  img0 + eoff[0][0], 8);
    __builtin_memcpy(&A1,  img0 + eoff[0][1], 8);
    __builtin_memcpy(&A2v, img0 + eoff[1][0], 8);
    __builtin_memcpy(&A3,  img0 + eoff[1][1], 8);
    __builtin_memcpy(&B0,  img1 + eoff[0][0], 8);
    __builtin_memcpy(&B1,  img1 + eoff[0][1], 8);
    __builtin_memcpy(&B2,  img1 + eoff[1][0], 8);
    __builtin_memcpy(&B3,  img1 + eoff[1][1], 8);
    __builtin_memcpy(&C0,  img2 + eoff[0][0], 8);
    __builtin_memcpy(&C1,  img2 + eoff[0][1], 8);
    __builtin_memcpy(&C2,  img2 + eoff[1][0], 8);
    __builtin_memcpy(&C3,  img2 + eoff[1][1], 8);
    // Cluster the 12 VMEM reads here, then the FMA tail.
    __builtin_amdgcn_sched_group_barrier(0x020, 12, 0);  // VMEM_READ x12
    __builtin_amdgcn_sched_group_barrier(0x002, 48, 0);  // VALU tail

    float r0a = fmaf(A0.x,  sw[0][0], fmaf(A0.y,  sw[0][1], fmaf(A1.x,  sw[0][2], A1.y  * sw[0][3])));
    float r1a = fmaf(A2v.x, sw[1][0], fmaf(A2v.y, sw[1][1], fmaf(A3.x,  sw[1][2], A3.y  * sw[1][3])));
    float r0b = fmaf(B0.x,  sw[0][0], fmaf(B0.y,  sw[0][1], fmaf(B1.x,  sw[0][2], B1.y  * sw[0][3])));
    float r1b = fmaf(B2.x,  sw[1][0], fmaf(B2.y,  sw[1][1], fmaf(B3.x,  sw[1][2], B3.y  * sw[1][3])));
    float r0c = fmaf(C0.x,  sw[0][0], fmaf(C0.y,  sw[0][1], fmaf(C1.x,  sw[0][2], C1.y  * sw[0][3])));
    float r1c = fmaf(C2.x,  sw[1][0], fmaf(C2.y,  sw[1][1], fmaf(C3.x,  sw[1][2], C3.y  * sw[1][3])));

    size_t p0 = (size_t)h0 * Wdim + w;
    size_t p1 = p0 + Wdim;
    __builtin_nontemporal_store(r0a, out + nbase + p0);
    __builtin_nontemporal_store(r1a, out + nbase + p1);
    __builtin_nontemporal_store(r0b, out + nbase + HW + p0);
    __builtin_nontemporal_store(r1b, out + nbase + HW + p1);
    __builtin_nontemporal_store(r0c, out + nbase + 2 * HW + p0);
    __builtin_nontemporal_store(r1c, out + nbase + 2 * HW + p1);
}

extern "C" void kernel_launch(void* const* d_in, const int* in_sizes, int n_in,
                              void* d_out, int out_size, void* d_ws, size_t ws_size,
                              hipStream_t stream) {
    const float* x     = (const float*)d_in[0];
    const float* theta = (const float*)d_in[1];
    float* out = (float*)d_out;
    float* th  = (float*)d_ws;  // 128*6 floats of scratch

    expm_kernel<<<1, 128, 0, stream>>>(theta, th);

    int nblocks = Ndim * (Hdim / 8) * (Wdim / 64);  // 16384
    sample_kernel<<<nblocks, 256, 0, stream>>>(x, th, out);
}

// Round 6
// 42.267 us; speedup vs baseline: 2.4790x; 1.0603x over previous
//
#include <hip/hip_runtime.h>

#define Ndim 128
#define Cdim 3
#define Hdim 256
#define Wdim 256
#define HW (Hdim * Wdim)
#define MAXNORM_F 5.371920351148152f

typedef float vf2 __attribute__((ext_vector_type(2)));
typedef float vf4 __attribute__((ext_vector_type(4)));

__device__ __forceinline__ void mm3f(const float a[3][3], const float b[3][3], float c[3][3]) {
    #pragma unroll
    for (int i = 0; i < 3; ++i)
        #pragma unroll
        for (int j = 0; j < 3; ++j) {
            float s = 0.0f;
            #pragma unroll
            for (int k = 0; k < 3; ++k) s = fmaf(a[i][k], b[k][j], s);
            c[i][j] = s;
        }
}

// One thread per batch element: expm of padded 3x3 affine matrix (fp32 Pade-13).
__global__ void expm_kernel(const float* __restrict__ theta, float* __restrict__ thOut) {
    int n = blockIdx.x * blockDim.x + threadIdx.x;
    if (n >= Ndim) return;

    const float b[14] = {6.476475253248e+16f, 3.238237626624e+16f, 7771770303897600.0f,
                         1187353796428800.0f, 129060195264000.0f, 10559470521600.0f,
                         670442572800.0f, 33522128640.0f, 1323241920.0f, 40840800.0f,
                         960960.0f, 16380.0f, 182.0f, 1.0f};

    float A[3][3];
    #pragma unroll
    for (int j = 0; j < 3; ++j) {
        A[0][j] = theta[n * 6 + j];
        A[1][j] = theta[n * 6 + 3 + j];
        A[2][j] = 0.0f;
    }

    float fro2 = 0.0f;
    #pragma unroll
    for (int i = 0; i < 3; ++i)
        #pragma unroll
        for (int j = 0; j < 3; ++j) fro2 = fmaf(A[i][j], A[i][j], fro2);
    float fro = sqrtf(fro2);

    float nsq = fmaxf(0.0f, ceilf(log2f(fro / MAXNORM_F)));
    int k = (int)nsq;
    float sc = exp2f(-nsq);
    #pragma unroll
    for (int i = 0; i < 3; ++i)
        #pragma unroll
        for (int j = 0; j < 3; ++j) A[i][j] *= sc;

    float A2[3][3], A4[3][3], A6[3][3], P[3][3], Wm[3][3], T[3][3], U[3][3], V[3][3];
    mm3f(A, A, A2);
    mm3f(A2, A2, A4);
    mm3f(A4, A2, A6);

    #pragma unroll
    for (int i = 0; i < 3; ++i)
        #pragma unroll
        for (int j = 0; j < 3; ++j)
            P[i][j] = b[13] * A6[i][j] + b[11] * A4[i][j] + b[9] * A2[i][j];
    mm3f(A6, P, T);
    #pragma unroll
    for (int i = 0; i < 3; ++i)
        #pragma unroll
        for (int j = 0; j < 3; ++j)
            Wm[i][j] = T[i][j] + b[7] * A6[i][j] + b[5] * A4[i][j] + b[3] * A2[i][j]
                       + (i == j ? b[1] : 0.0f);
    mm3f(A, Wm, U);

    #pragma unroll
    for (int i = 0; i < 3; ++i)
        #pragma unroll
        for (int j = 0; j < 3; ++j)
            P[i][j] = b[12] * A6[i][j] + b[10] * A4[i][j] + b[8] * A2[i][j];
    mm3f(A6, P, T);
    #pragma unroll
    for (int i = 0; i < 3; ++i)
        #pragma unroll
        for (int j = 0; j < 3; ++j)
            V[i][j] = T[i][j] + b[6] * A6[i][j] + b[4] * A4[i][j] + b[2] * A2[i][j]
                      + (i == j ? b[0] : 0.0f);

    float M[3][6];
    #pragma unroll
    for (int i = 0; i < 3; ++i)
        #pragma unroll
        for (int j = 0; j < 3; ++j) {
            M[i][j]     = U[i][j] + V[i][j];
            M[i][j + 3] = V[i][j] - U[i][j];
        }
    #pragma unroll
    for (int col = 0; col < 3; ++col) {
        int piv = col;
        float best = fabsf(M[col][col]);
        for (int r = col + 1; r < 3; ++r) {
            float v = fabsf(M[r][col]);
            if (v > best) { best = v; piv = r; }
        }
        if (piv != col) {
            #pragma unroll
            for (int j = 0; j < 6; ++j) {
                float t = M[col][j]; M[col][j] = M[piv][j]; M[piv][j] = t;
            }
        }
        float inv = 1.0f / M[col][col];
        #pragma unroll
        for (int j = 0; j < 6; ++j) M[col][j] *= inv;
        #pragma unroll
        for (int r = 0; r < 3; ++r) {
            if (r == col) continue;
            float f = M[r][col];
            #pragma unroll
            for (int j = 0; j < 6; ++j) M[r][j] -= f * M[col][j];
        }
    }
    float R[3][3];
    #pragma unroll
    for (int i = 0; i < 3; ++i)
        #pragma unroll
        for (int j = 0; j < 3; ++j) R[i][j] = M[i][j + 3];

    for (int i = 0; i < 16; ++i) {
        if (i < k) {
            float Rn[3][3];
            mm3f(R, R, Rn);
            #pragma unroll
            for (int a = 0; a < 3; ++a)
                #pragma unroll
                for (int c = 0; c < 3; ++c) R[a][c] = Rn[a][c];
        }
    }

    #pragma unroll
    for (int j = 0; j < 3; ++j) {
        thOut[n * 6 + j]     = (float)R[0][j];
        thOut[n * 6 + 3 + j] = (float)R[1][j];
    }
}

// Fused affine_grid + bilinear grid_sample (zeros padding, align_corners=True).
// Each thread computes a 2x2 output quad. Since W==H==256:
//   ix = w*t0 + h*t1 + Cx,  iy = w*t3 + h*t4 + Cy.
// Quad coordinate range: x: |t0|+|t1|, y: |t3|+|t4|. When both < 2, all 16
// bilinear corners of the quad fit in a 4x4 input window -> per channel load
// 4 rows as dwordx4 (12 gathers + 6 dwordx2 stores per 4 px = 4.5 VMEM/px,
// half of R5). Corner selection inside the window is branchless: per-pixel
// 4-wide weight vectors (zeros off-corner) + dot products. Clamp semantics:
// row slot i holds input row clamp(Ymin+i); x-rel index uses
// clamp(corner)-clamp(Xmin) which provably stays in [0,3].
__global__ __launch_bounds__(256) void sample_kernel(const float* __restrict__ x,
                                                     const float* __restrict__ th,
                                                     float* __restrict__ out) {
    // tiles: 4 (w) * 16 (h) * 128 (n) = 8192 blocks, divisible by 8
    const int nwg_per_xcd = 8192 / 8;
    int bid = blockIdx.x;
    int wgid = (bid & 7) * nwg_per_xcd + (bid >> 3);

    int tw  = wgid & 3;          // w-tile (64 px)
    int thp = (wgid >> 2) & 15;  // h-tile (16 px)
    int n   = wgid >> 6;         // image

    int tid = threadIdx.x;
    int wp  = tid & 31;          // 32 w-pairs
    int hp  = tid >> 5;          // 8 h-pairs
    int w0  = (tw << 6) + (wp << 1);
    int h0  = (thp << 4) + (hp << 1);

    const float* t = th + n * 6;
    float t0 = t[0], t1 = t[1], t2 = t[2], t3 = t[3], t4 = t[4], t5 = t[5];

    float Cx = 127.5f * (t2 - t0 - t1 + 1.0f);
    float Cy = 127.5f * (t5 - t3 - t4 + 1.0f);

    float ix00 = fmaf((float)w0, t0, fmaf((float)h0, t1, Cx));
    float iy00 = fmaf((float)w0, t3, fmaf((float)h0, t4, Cy));
    // quad coords: [p(row)][q(col)]
    float ix[2][2] = {{ix00, ix00 + t0}, {ix00 + t1, ix00 + t0 + t1}};
    float iy[2][2] = {{iy00, iy00 + t3}, {iy00 + t4, iy00 + t3 + t4}};

    size_t nbase = (size_t)n * Cdim * HW;
    bool fast = (fabsf(t0) + fabsf(t1) < 2.0f) && (fabsf(t3) + fabsf(t4) < 2.0f);

    if (fast) {
        float Xminf = fminf(fminf(ix[0][0], ix[0][1]), fminf(ix[1][0], ix[1][1]));
        float Yminf = fminf(fminf(iy[0][0], iy[0][1]), fminf(iy[1][0], iy[1][1]));
        int Xmin = (int)floorf(Xminf);
        int Ymin = (int)floorf(Yminf);
        int bx = min(max(Xmin, 0), Wdim - 4);

        // per-pixel weight vectors over the 4x4 window
        float wxv[2][2][4], wyv[2][2][4];
        #pragma unroll
        for (int p = 0; p < 2; ++p)
            #pragma unroll
            for (int q = 0; q < 2; ++q) {
                float fx = floorf(ix[p][q]);
                float fy = floorf(iy[p][q]);
                int ixi = (int)fx, iyi = (int)fy;
                float wx1 = ix[p][q] - fx, wx0 = 1.0f - wx1;
                float wy1 = iy[p][q] - fy, wy0 = 1.0f - wy1;
                float mx0 = ((unsigned)ixi       < (unsigned)Wdim) ? 1.0f : 0.0f;
                float mx1 = ((unsigned)(ixi + 1) < (unsigned)Wdim) ? 1.0f : 0.0f;
                float my0 = ((unsigned)iyi       < (unsigned)Hdim) ? 1.0f : 0.0f;
                float my1 = ((unsigned)(iyi + 1) < (unsigned)Hdim) ? 1.0f : 0.0f;
                float wxm0 = wx0 * mx0, wxm1 = wx1 * mx1;
                float wym0 = wy0 * my0, wym1 = wy1 * my1;

                int cxa = min(max(ixi, 0), Wdim - 1) - bx;
                int cxb = min(max(ixi + 1, 0), Wdim - 1) - bx;
                int rya = iyi - Ymin;            // in [0,2]; ryb = rya+1
                #pragma unroll
                for (int j = 0; j < 4; ++j) {
                    wxv[p][q][j] = (j == cxa ? wxm0 : 0.0f) + (j == cxb ? wxm1 : 0.0f);
                    wyv[p][q][j] = (j == rya ? wym0 : 0.0f) + (j == rya + 1 ? wym1 : 0.0f);
                }
            }

        // row voffsets (element units), rows clamped individually
        int roff[4];
        #pragma unroll
        for (int i = 0; i < 4; ++i) {
            int r = min(max(Ymin + i, 0), Hdim - 1);
            roff[i] = (r << 8) + bx;
        }

        // 12 independent dwordx4 gathers
        const float* img0 = x + nbase;
        const float* img1 = img0 + HW;
        const float* img2 = img1 + HW;
        vf4 R0[4], R1[4], R2[4];
        #pragma unroll
        for (int i = 0; i < 4; ++i) __builtin_memcpy(&R0[i], img0 + roff[i], 16);
        #pragma unroll
        for (int i = 0; i < 4; ++i) __builtin_memcpy(&R1[i], img1 + roff[i], 16);
        #pragma unroll
        for (int i = 0; i < 4; ++i) __builtin_memcpy(&R2[i], img2 + roff[i], 16);

        size_t p0 = (size_t)h0 * Wdim + w0;
        size_t p1 = p0 + Wdim;

        #pragma unroll
        for (int c = 0; c < Cdim; ++c) {
            const vf4* Rw = (c == 0) ? R0 : (c == 1) ? R1 : R2;
            float res[2][2];
            #pragma unroll
            for (int p = 0; p < 2; ++p)
                #pragma unroll
                for (int q = 0; q < 2; ++q) {
                    float s = 0.0f;
                    #pragma unroll
                    for (int i = 0; i < 4; ++i) {
                        vf4 rv = Rw[i];
                        float d = fmaf(rv.x, wxv[p][q][0],
                                  fmaf(rv.y, wxv[p][q][1],
                                  fmaf(rv.z, wxv[p][q][2],
                                       rv.w * wxv[p][q][3])));
                        s = fmaf(wyv[p][q][i], d, s);
                    }
                    res[p][q] = s;
                }
            vf2 r0 = {res[0][0], res[0][1]};
            vf2 r1 = {res[1][0], res[1][1]};
            __builtin_nontemporal_store(r0, (vf2*)(out + nbase + (size_t)c * HW + p0));
            __builtin_nontemporal_store(r1, (vf2*)(out + nbase + (size_t)c * HW + p1));
        }
    } else {
        // General fallback (never taken for this input's near-identity thetas):
        // exact per-pixel scalar gathers.
        const float* img0 = x + nbase;
        #pragma unroll
        for (int p = 0; p < 2; ++p)
            #pragma unroll
            for (int q = 0; q < 2; ++q) {
                float fx = floorf(ix[p][q]);
                float fy = floorf(iy[p][q]);
                int ix0 = (int)fx, iy0 = (int)fy;
                float wx1 = ix[p][q] - fx, wx0 = 1.0f - wx1;
                float wy1 = iy[p][q] - fy, wy0 = 1.0f - wy1;
                float mx0 = ((unsigned)ix0       < (unsigned)Wdim) ? 1.0f : 0.0f;
                float mx1 = ((unsigned)(ix0 + 1) < (unsigned)Wdim) ? 1.0f : 0.0f;
                float my0 = ((unsigned)iy0       < (unsigned)Hdim) ? 1.0f : 0.0f;
                float my1 = ((unsigned)(iy0 + 1) < (unsigned)Hdim) ? 1.0f : 0.0f;
                int xc0 = min(max(ix0, 0), Wdim - 1);
                int xc1 = min(max(ix0 + 1, 0), Wdim - 1);
                int yc0 = min(max(iy0, 0), Hdim - 1);
                int yc1 = min(max(iy0 + 1, 0), Hdim - 1);
                float w00 = wy0 * wx0 * my0 * mx0;
                float w01 = wy0 * wx1 * my0 * mx1;
                float w10 = wy1 * wx0 * my1 * mx0;
                float w11 = wy1 * wx1 * my1 * mx1;
                int o00 = yc0 * Wdim + xc0, o01 = yc0 * Wdim + xc1;
                int o10 = yc1 * Wdim + xc0, o11 = yc1 * Wdim + xc1;
                #pragma unroll
                for (int c = 0; c < Cdim; ++c) {
                    const float* img = img0 + (size_t)c * HW;
                    float r = fmaf(img[o00], w00, fmaf(img[o01], w01,
                              fmaf(img[o10], w10, img[o11] * w11)));
                    out[nbase + (size_t)c * HW + (size_t)(h0 + p) * Wdim + (w0 + q)] = r;
                }
            }
    }
}

extern "C" void kernel_launch(void* const* d_in, const int* in_sizes, int n_in,
                              void* d_out, int out_size, void* d_ws, size_t ws_size,
                              hipStream_t stream) {
    const float* x     = (const float*)d_in[0];
    const float* theta = (const float*)d_in[1];
    float* out = (float*)d_out;
    float* th  = (float*)d_ws;  // 128*6 floats of scratch

    expm_kernel<<<1, 128, 0, stream>>>(theta, th);

    int nblocks = Ndim * 16 * 4;  // 8192
    sample_kernel<<<nblocks, 256, 0, stream>>>(x, th, out);
}